// Round 1
// baseline (1587.315 us; speedup 1.0000x reference)
//
#include <hip/hip_runtime.h>
#include <hip/hip_bf16.h>

// MoE: B=4,S=4096,D=512,E=16,H=2048,top-2. T=16384 tokens, 32768 assignments.
#define T_TOK 16384
#define DDIM  512
#define NEXP  16
#define HDIM  2048
#define NSLOT (T_TOK * 2)

#define BM 256
#define BN 128
#define MT 64   // max m-tiles per expert = T_TOK/BM

typedef __attribute__((ext_vector_type(8))) short short8;   // 8 x bf16 (4 VGPR)
typedef __attribute__((ext_vector_type(4))) short short4v;
typedef __attribute__((ext_vector_type(4))) float f32x4;

__device__ inline short f2bf(float f) {
    __hip_bfloat16 h = __float2bfloat16(f);
    return *reinterpret_cast<short*>(&h);
}
__device__ inline float geluf(float v) {   // exact gelu: x*0.5*(1+erf(x/sqrt(2)))
    return 0.5f * v * (1.0f + erff(v * 0.70710678118654752440f));
}

// ---------------- routing ----------------

__global__ __launch_bounds__(256) void gate_kernel(
    const float* __restrict__ x, const float* __restrict__ wg,
    const float* __restrict__ bg, int* __restrict__ tok_e,
    float* __restrict__ tok_w, int* __restrict__ counts)
{
    __shared__ float xs[16 * DDIM];
    __shared__ double lgd[16][17];
    int tid = threadIdx.x;
    long t0 = (long)blockIdx.x * 16;
    const float4* xi = (const float4*)(x + t0 * DDIM);
    float4* xs4 = (float4*)xs;
#pragma unroll
    for (int i = 0; i < 8; ++i) xs4[tid + 256 * i] = xi[tid + 256 * i];
    __syncthreads();
    int lt = tid >> 4, e = tid & 15;
    const float* xr = xs + lt * DDIM;
    // fp64 accumulation: tie-robust top-k vs the (near-exact) reference
    double a0 = 0, a1 = 0, a2 = 0, a3 = 0;
#pragma unroll 4
    for (int d = 0; d < DDIM; d += 4) {
        a0 += (double)xr[d]     * (double)wg[(d)     * NEXP + e];
        a1 += (double)xr[d + 1] * (double)wg[(d + 1) * NEXP + e];
        a2 += (double)xr[d + 2] * (double)wg[(d + 2) * NEXP + e];
        a3 += (double)xr[d + 3] * (double)wg[(d + 3) * NEXP + e];
    }
    lgd[lt][e] = ((a0 + a1) + (a2 + a3)) + (double)bg[e];
    __syncthreads();
    if (tid < 16) {
        int t = (int)t0 + tid;
        double v0 = -1e300; int i0 = 0;
#pragma unroll
        for (int k = 0; k < 16; ++k) { double v = lgd[tid][k]; if (v > v0) { v0 = v; i0 = k; } }
        double v1 = -1e300; int i1 = 0;
#pragma unroll
        for (int k = 0; k < 16; ++k) { if (k != i0) { double v = lgd[tid][k]; if (v > v1) { v1 = v; i1 = k; } } }
        float ex = expf((float)(v1 - v0));      // <= 1
        float w0 = 1.0f / (1.0f + ex);
        float w1 = ex * w0;
        tok_e[2 * t] = i0; tok_e[2 * t + 1] = i1;
        tok_w[2 * t] = w0; tok_w[2 * t + 1] = w1;
        atomicAdd(&counts[i0], 1);
        atomicAdd(&counts[i1], 1);
    }
}

__global__ void scan_kernel(const int* __restrict__ counts, int* __restrict__ offs,
                            int* __restrict__ cursors)
{
    if (threadIdx.x == 0) {
        int run = 0;
        for (int e = 0; e < NEXP; ++e) { offs[e] = run; cursors[e] = run; run += counts[e]; }
        offs[NEXP] = run;   // == NSLOT
    }
}

__global__ void scatter_kernel(const int* __restrict__ tok_e, const float* __restrict__ tok_w,
                               int* __restrict__ cursors, int* __restrict__ list_tok,
                               float* __restrict__ list_w)
{
    int t = blockIdx.x * blockDim.x + threadIdx.x;
    if (t >= T_TOK) return;
#pragma unroll
    for (int k = 0; k < 2; ++k) {
        int e = tok_e[2 * t + k];
        int pos = atomicAdd(&cursors[e], 1);
        list_tok[pos] = t;
        list_w[pos] = tok_w[2 * t + k];
    }
}

// ---------------- pre-conversion ----------------

__global__ void cvt_bf16_kernel(const float* __restrict__ src, short* __restrict__ dst, int n4)
{
    int i = blockIdx.x * blockDim.x + threadIdx.x;
    int stride = gridDim.x * blockDim.x;
    for (; i < n4; i += stride) {
        float4 v = ((const float4*)src)[i];
        short4v o;
        o[0] = f2bf(v.x); o[1] = f2bf(v.y); o[2] = f2bf(v.z); o[3] = f2bf(v.w);
        ((short4v*)dst)[i] = o;
    }
}

// transpose one [R][C] fp32 matrix per blockIdx.z into [C][R] bf16
__global__ void wtrans_kernel(const float* __restrict__ src, short* __restrict__ dst, int R, int C)
{
    __shared__ float t[32][33];
    int c0 = blockIdx.x * 32, r0 = blockIdx.y * 32;
    const float* s = src + (size_t)blockIdx.z * R * C;
    short* d = dst + (size_t)blockIdx.z * R * C;
    int cc = threadIdx.x & 31, rr = threadIdx.x >> 5;
#pragma unroll
    for (int pp = 0; pp < 4; ++pp)
        t[rr + pp * 8][cc] = s[(size_t)(r0 + rr + pp * 8) * C + c0 + cc];
    __syncthreads();
#pragma unroll
    for (int pp = 0; pp < 4; ++pp) {
        int c = rr + pp * 8;
        d[(size_t)(c0 + c) * R + r0 + cc] = f2bf(t[cc][c]);
    }
}

// ---------------- expert GEMMs ----------------
// Both use: 256x128 tile, 512 threads (8 waves, 4m x 2n), 64x64 wave tile,
// mfma_f32_16x16x32_bf16, XOR-swizzled LDS (byte ^= (row&7)<<4), KC=64.

__global__ __launch_bounds__(512) void gemm1_kernel(
    const short* __restrict__ xbf, const short* __restrict__ w1t,
    const float* __restrict__ b1, const int* __restrict__ offs,
    const int* __restrict__ list_tok, short* __restrict__ hbuf,
    int h0, int hlen)
{
    int e = blockIdx.x >> 6, mt = blockIdx.x & 63;
    int m0 = offs[e] + mt * BM;
    int mend = offs[e + 1];
    if (m0 >= mend) return;
    int rows = min(BM, mend - m0);
    int n0 = blockIdx.y * BN;          // chunk-relative h
    int tid = threadIdx.x;
    int lane = tid & 63, wid = tid >> 6;
    int wm = wid >> 1, wn = wid & 1;

    __shared__ __align__(16) short As[BM * 64];
    __shared__ __align__(16) short Bs[BN * 64];
    __shared__ int ts[BM];

    if (tid < BM) ts[tid] = list_tok[(tid < rows) ? (m0 + tid) : m0];
    __syncthreads();

    int ar = tid >> 1, aq = tid & 1;     // A staging: row, 32-elem half
    int bn = tid >> 2, bsg = tid & 3;    // B staging: row, 16-elem seg
    const short* aptr = xbf + (size_t)ts[ar] * DDIM + aq * 32;
    const short* bptr = w1t + ((size_t)e * HDIM + (size_t)(h0 + n0 + bn)) * DDIM + bsg * 16;

    f32x4 vzero = {0.0f, 0.0f, 0.0f, 0.0f};
    f32x4 acc[4][4];
#pragma unroll
    for (int i = 0; i < 4; ++i)
#pragma unroll
        for (int j = 0; j < 4; ++j) acc[i][j] = vzero;

    int a_r = wm * 64 + (lane & 15);
    int b_r = wn * 64 + (lane & 15);
    int kf = (lane >> 4) * 8;
    int aswz = (a_r & 7) << 4;
    int bswz = (b_r & 7) << 4;
    int sw = (ar & 7) << 4;
    int swb = (bn & 7) << 4;

    short8 av0, av1, av2, av3, bv0, bv1;
#define G1_LOAD(KB) {                                          \
        const short* ap = aptr + (KB) * 64;                    \
        av0 = *(const short8*)(ap);                            \
        av1 = *(const short8*)(ap + 8);                        \
        av2 = *(const short8*)(ap + 16);                       \
        av3 = *(const short8*)(ap + 24);                       \
        const short* bp = bptr + (KB) * 64;                    \
        bv0 = *(const short8*)(bp);                            \
        bv1 = *(const short8*)(bp + 8); }
#define G1_STORE() {                                           \
        char* abase = (char*)As + ar * 128;                    \
        *(short8*)(abase + ((aq * 64 +  0) ^ sw)) = av0;       \
        *(short8*)(abase + ((aq * 64 + 16) ^ sw)) = av1;       \
        *(short8*)(abase + ((aq * 64 + 32) ^ sw)) = av2;       \
        *(short8*)(abase + ((aq * 64 + 48) ^ sw)) = av3;       \
        char* bbase = (char*)Bs + bn * 128;                    \
        *(short8*)(bbase + ((bsg * 32 +  0) ^ swb)) = bv0;     \
        *(short8*)(bbase + ((bsg * 32 + 16) ^ swb)) = bv1; }

    G1_LOAD(0);
    for (int kb = 0; kb < 8; ++kb) {
        __syncthreads();
        G1_STORE();
        __syncthreads();
        if (kb < 7) G1_LOAD(kb + 1);
#pragma unroll
        for (int ks = 0; ks < 2; ++ks) {
            short8 af[4], bfr[4];
            int kbyte = (ks * 32 + kf) * 2;
#pragma unroll
            for (int mi = 0; mi < 4; ++mi)
                af[mi] = *(const short8*)((char*)As + (a_r + mi * 16) * 128 + (kbyte ^ aswz));
#pragma unroll
            for (int ni = 0; ni < 4; ++ni)
                bfr[ni] = *(const short8*)((char*)Bs + (b_r + ni * 16) * 128 + (kbyte ^ bswz));
#pragma unroll
            for (int mi = 0; mi < 4; ++mi)
#pragma unroll
                for (int ni = 0; ni < 4; ++ni)
                    acc[mi][ni] = __builtin_amdgcn_mfma_f32_16x16x32_bf16(
                        af[mi], bfr[ni], acc[mi][ni], 0, 0, 0);
        }
    }

    // epilogue: +b1, exact gelu, bf16 store to hbuf
    int crow = wm * 64 + ((lane >> 4) << 2);
    int ccol = wn * 64 + (lane & 15);
#pragma unroll
    for (int mi = 0; mi < 4; ++mi) {
#pragma unroll
        for (int ni = 0; ni < 4; ++ni) {
            int col = ccol + ni * 16;
            float bias = b1[e * HDIM + h0 + n0 + col];
#pragma unroll
            for (int j = 0; j < 4; ++j) {
                int row = crow + mi * 16 + j;
                if (row < rows) {
                    float v = acc[mi][ni][j] + bias;
                    hbuf[(size_t)(m0 + row) * hlen + (n0 + col)] = f2bf(geluf(v));
                }
            }
        }
    }
}

__global__ __launch_bounds__(512) void gemm2_kernel(
    const short* __restrict__ hbuf, const short* __restrict__ w2t,
    const float* __restrict__ b2, const int* __restrict__ offs,
    const int* __restrict__ list_tok, const float* __restrict__ list_w,
    float* __restrict__ out, int h0, int hlen, int addb2)
{
    int e = blockIdx.x >> 6, mt = blockIdx.x & 63;
    int m0 = offs[e] + mt * BM;
    int mend = offs[e + 1];
    if (m0 >= mend) return;
    int rows = min(BM, mend - m0);
    int n0 = blockIdx.y * BN;          // output d coordinate
    int tid = threadIdx.x;
    int lane = tid & 63, wid = tid >> 6;
    int wm = wid >> 1, wn = wid & 1;

    __shared__ __align__(16) short As[BM * 64];
    __shared__ __align__(16) short Bs[BN * 64];
    __shared__ int ts[BM];
    __shared__ float lw[BM];

    if (tid < BM) {
        int idx = (tid < rows) ? (m0 + tid) : m0;
        ts[tid] = list_tok[idx];
        lw[tid] = list_w[idx];
    }
    __syncthreads();

    int ar = tid >> 1, aq = tid & 1;
    int bn = tid >> 2, bsg = tid & 3;
    int arow = m0 + ar; if (arow >= NSLOT) arow = NSLOT - 1;
    const short* aptr = hbuf + (size_t)arow * hlen + aq * 32;
    const short* bptr = w2t + ((size_t)e * DDIM + (size_t)(n0 + bn)) * HDIM + h0 + bsg * 16;

    f32x4 vzero = {0.0f, 0.0f, 0.0f, 0.0f};
    f32x4 acc[4][4];
#pragma unroll
    for (int i = 0; i < 4; ++i)
#pragma unroll
        for (int j = 0; j < 4; ++j) acc[i][j] = vzero;

    int a_r = wm * 64 + (lane & 15);
    int b_r = wn * 64 + (lane & 15);
    int kf = (lane >> 4) * 8;
    int aswz = (a_r & 7) << 4;
    int bswz = (b_r & 7) << 4;
    int sw = (ar & 7) << 4;
    int swb = (bn & 7) << 4;

    short8 av0, av1, av2, av3, bv0, bv1;
    int nkb = hlen >> 6;
    {
        const short* ap = aptr;
        av0 = *(const short8*)(ap);      av1 = *(const short8*)(ap + 8);
        av2 = *(const short8*)(ap + 16); av3 = *(const short8*)(ap + 24);
        const short* bp = bptr;
        bv0 = *(const short8*)(bp);      bv1 = *(const short8*)(bp + 8);
    }
    for (int kb = 0; kb < nkb; ++kb) {
        __syncthreads();
        {
            char* abase = (char*)As + ar * 128;
            *(short8*)(abase + ((aq * 64 +  0) ^ sw)) = av0;
            *(short8*)(abase + ((aq * 64 + 16) ^ sw)) = av1;
            *(short8*)(abase + ((aq * 64 + 32) ^ sw)) = av2;
            *(short8*)(abase + ((aq * 64 + 48) ^ sw)) = av3;
            char* bbase = (char*)Bs + bn * 128;
            *(short8*)(bbase + ((bsg * 32 +  0) ^ swb)) = bv0;
            *(short8*)(bbase + ((bsg * 32 + 16) ^ swb)) = bv1;
        }
        __syncthreads();
        if (kb + 1 < nkb) {
            const short* ap = aptr + (kb + 1) * 64;
            av0 = *(const short8*)(ap);      av1 = *(const short8*)(ap + 8);
            av2 = *(const short8*)(ap + 16); av3 = *(const short8*)(ap + 24);
            const short* bp = bptr + (kb + 1) * 64;
            bv0 = *(const short8*)(bp);      bv1 = *(const short8*)(bp + 8);
        }
#pragma unroll
        for (int ks = 0; ks < 2; ++ks) {
            short8 af[4], bfr[4];
            int kbyte = (ks * 32 + kf) * 2;
#pragma unroll
            for (int mi = 0; mi < 4; ++mi)
                af[mi] = *(const short8*)((char*)As + (a_r + mi * 16) * 128 + (kbyte ^ aswz));
#pragma unroll
            for (int ni = 0; ni < 4; ++ni)
                bfr[ni] = *(const short8*)((char*)Bs + (b_r + ni * 16) * 128 + (kbyte ^ bswz));
#pragma unroll
            for (int mi = 0; mi < 4; ++mi)
#pragma unroll
                for (int ni = 0; ni < 4; ++ni)
                    acc[mi][ni] = __builtin_amdgcn_mfma_f32_16x16x32_bf16(
                        af[mi], bfr[ni], acc[mi][ni], 0, 0, 0);
        }
    }

    // epilogue: (+b2 on first chunk), scale by gate weight, atomic accumulate
    int crow = wm * 64 + ((lane >> 4) << 2);
    int ccol = wn * 64 + (lane & 15);
#pragma unroll
    for (int mi = 0; mi < 4; ++mi) {
#pragma unroll
        for (int ni = 0; ni < 4; ++ni) {
            int col = ccol + ni * 16;
            float bias = addb2 ? b2[e * DDIM + n0 + col] : 0.0f;
#pragma unroll
            for (int j = 0; j < 4; ++j) {
                int row = crow + mi * 16 + j;
                if (row < rows) {
                    float v = acc[mi][ni][j] + bias;
                    atomicAdd(&out[(size_t)ts[row] * DDIM + n0 + col], lw[row] * v);
                }
            }
        }
    }
}

// ---------------- launch ----------------

extern "C" void kernel_launch(void* const* d_in, const int* in_sizes, int n_in,
                              void* d_out, int out_size, void* d_ws, size_t ws_size,
                              hipStream_t stream)
{
    const float* x  = (const float*)d_in[0];
    const float* wg = (const float*)d_in[1];
    const float* bg = (const float*)d_in[2];
    const float* w1 = (const float*)d_in[3];
    const float* b1 = (const float*)d_in[4];
    const float* w2 = (const float*)d_in[5];
    const float* b2 = (const float*)d_in[6];
    float* out = (float*)d_out;

    char* p = (char*)d_ws;
    int* counts   = (int*)(p);                    // 64 B
    int* cursors  = (int*)(p + 64);               // 64 B
    int* offs     = (int*)(p + 128);              // 128 B (17 ints)
    int* tok_e    = (int*)(p + 256);              // 2T ints  = 131072 B
    float* tok_w  = (float*)(p + 256 + 131072);   // 131072 B
    int* list_tok = (int*)(p + 256 + 262144);     // 131072 B
    float* list_w = (float*)(p + 256 + 393216);   // 131072 B
    short* xbf    = (short*)(p + 256 + 524288);                    // 16 MiB
    short* w1t    = (short*)(p + 256 + 524288 + 16777216);         // 32 MiB
    short* w2t    = w1t + (size_t)NEXP * DDIM * HDIM;              // 32 MiB
    short* hbuf   = w2t + (size_t)NEXP * DDIM * HDIM;
    size_t fixed_bytes = 256 + 524288 + 16777216 + 2 * 33554432;   // 84,410,624

    int hlen = 0;
    for (int s = 1; s <= 16; s <<= 1) {
        size_t need = fixed_bytes + (size_t)NSLOT * (size_t)(HDIM / s) * 2;
        if (need <= ws_size) { hlen = HDIM / s; break; }
    }

    hipMemsetAsync(d_out, 0, (size_t)out_size * sizeof(float), stream);
    if (!hlen) return;   // ws too small: leave out zeroed (signals via absmax==2.64)
    hipMemsetAsync(counts, 0, 64, stream);

    gate_kernel<<<T_TOK / 16, 256, 0, stream>>>(x, wg, bg, tok_e, tok_w, counts);
    scan_kernel<<<1, 64, 0, stream>>>(counts, offs, cursors);
    scatter_kernel<<<T_TOK / 256, 256, 0, stream>>>(tok_e, tok_w, cursors, list_tok, list_w);
    cvt_bf16_kernel<<<2048, 256, 0, stream>>>(x, xbf, T_TOK * DDIM / 4);
    wtrans_kernel<<<dim3(HDIM / 32, DDIM / 32, NEXP), 256, 0, stream>>>(w1, w1t, DDIM, HDIM);
    wtrans_kernel<<<dim3(DDIM / 32, HDIM / 32, NEXP), 256, 0, stream>>>(w2, w2t, HDIM, DDIM);

    for (int h0 = 0; h0 < HDIM; h0 += hlen) {
        gemm1_kernel<<<dim3(NEXP * MT, hlen / BN), 512, 0, stream>>>(
            xbf, w1t, b1, offs, list_tok, hbuf, h0, hlen);
        gemm2_kernel<<<dim3(NEXP * MT, DDIM / BN), 512, 0, stream>>>(
            hbuf, w2t, b2, offs, list_tok, list_w, out, h0, hlen, h0 == 0 ? 1 : 0);
    }
}

// Round 2
// 681.744 us; speedup vs baseline: 2.3283x; 2.3283x over previous
//
#include <hip/hip_runtime.h>
#include <hip/hip_bf16.h>

// MoE: B=4,S=4096,D=512,E=16,H=2048,top-2. T=16384 tokens, 32768 slots.
#define T_TOK 16384
#define DDIM  512
#define NEXP  16
#define HDIM  2048
#define NSLOT (T_TOK * 2)

#define GBM 128           // gemm tile M
#define GBN 128           // gemm tile N
#define MAXTILE 272       // max m-tiles: 32768/128 + 16

typedef __attribute__((ext_vector_type(8))) short short8;   // 8 x bf16
typedef __attribute__((ext_vector_type(4))) short short4v;
typedef __attribute__((ext_vector_type(4))) float f32x4;

__device__ inline short f2bf(float f) {
    __hip_bfloat16 h = __float2bfloat16(f);
    return *reinterpret_cast<short*>(&h);
}
__device__ inline float geluf(float v) {   // exact gelu
    return 0.5f * v * (1.0f + erff(v * 0.70710678118654752440f));
}
// async global->LDS, 16B per lane. LDS dest = uniform base + lane*16.
__device__ inline void gload16(const void* g, void* l) {
    __builtin_amdgcn_global_load_lds(
        (const __attribute__((address_space(1))) void*)g,
        (__attribute__((address_space(3))) void*)l, 16, 0, 0);
}

// ---------------- routing ----------------

__global__ __launch_bounds__(256) void gate_kernel(
    const float* __restrict__ x, const float* __restrict__ wg,
    const float* __restrict__ bg, int* __restrict__ tok_e,
    float* __restrict__ tok_w, int* __restrict__ counts)
{
    __shared__ float xs[16 * DDIM];
    __shared__ double lgd[16][17];
    int tid = threadIdx.x;
    long t0 = (long)blockIdx.x * 16;
    const float4* xi = (const float4*)(x + t0 * DDIM);
    float4* xs4 = (float4*)xs;
#pragma unroll
    for (int i = 0; i < 8; ++i) xs4[tid + 256 * i] = xi[tid + 256 * i];
    __syncthreads();
    int lt = tid >> 4, e = tid & 15;
    const float* xr = xs + lt * DDIM;
    double a0 = 0, a1 = 0, a2 = 0, a3 = 0;   // fp64: tie-robust top-k
#pragma unroll 4
    for (int d = 0; d < DDIM; d += 4) {
        a0 += (double)xr[d]     * (double)wg[(d)     * NEXP + e];
        a1 += (double)xr[d + 1] * (double)wg[(d + 1) * NEXP + e];
        a2 += (double)xr[d + 2] * (double)wg[(d + 2) * NEXP + e];
        a3 += (double)xr[d + 3] * (double)wg[(d + 3) * NEXP + e];
    }
    lgd[lt][e] = ((a0 + a1) + (a2 + a3)) + (double)bg[e];
    __syncthreads();
    if (tid < 16) {
        int t = (int)t0 + tid;
        double v0 = -1e300; int i0 = 0;
#pragma unroll
        for (int k = 0; k < 16; ++k) { double v = lgd[tid][k]; if (v > v0) { v0 = v; i0 = k; } }
        double v1 = -1e300; int i1 = 0;
#pragma unroll
        for (int k = 0; k < 16; ++k) { if (k != i0) { double v = lgd[tid][k]; if (v > v1) { v1 = v; i1 = k; } } }
        float ex = expf((float)(v1 - v0));
        float w0 = 1.0f / (1.0f + ex);
        float w1 = ex * w0;
        tok_e[2 * t] = i0; tok_e[2 * t + 1] = i1;
        tok_w[2 * t] = w0; tok_w[2 * t + 1] = w1;
        atomicAdd(&counts[i0], 1);
        atomicAdd(&counts[i1], 1);
    }
}

// offs[0..16] = exclusive scan; offs[17] = ntiles; builds compact tile table
__global__ void scan_kernel(const int* __restrict__ counts, int* __restrict__ offs,
                            int* __restrict__ cursors, int* __restrict__ tile_e,
                            int* __restrict__ tile_m0)
{
    if (threadIdx.x == 0) {
        int run = 0;
        for (int e = 0; e < NEXP; ++e) { offs[e] = run; cursors[e] = run; run += counts[e]; }
        offs[NEXP] = run;
        int nt = 0;
        for (int e = 0; e < NEXP; ++e)
            for (int m = offs[e]; m < offs[e + 1]; m += GBM) {
                tile_e[nt] = e; tile_m0[nt] = m; ++nt;
            }
        offs[17] = nt;
    }
}

__global__ void scatter_kernel(const int* __restrict__ tok_e, const float* __restrict__ tok_w,
                               int* __restrict__ cursors, int* __restrict__ list_tok,
                               float* __restrict__ list_w, int* __restrict__ pos_tk)
{
    int t = blockIdx.x * blockDim.x + threadIdx.x;
    if (t >= T_TOK) return;
#pragma unroll
    for (int k = 0; k < 2; ++k) {
        int e = tok_e[2 * t + k];
        int pos = atomicAdd(&cursors[e], 1);
        list_tok[pos] = t;
        list_w[pos] = tok_w[2 * t + k];
        pos_tk[2 * t + k] = pos;
    }
}

// ---------------- pre-conversion ----------------

__global__ void cvt_bf16_kernel(const float* __restrict__ src, short* __restrict__ dst, int n4)
{
    int i = blockIdx.x * blockDim.x + threadIdx.x;
    int stride = gridDim.x * blockDim.x;
    for (; i < n4; i += stride) {
        float4 v = ((const float4*)src)[i];
        short4v o;
        o[0] = f2bf(v.x); o[1] = f2bf(v.y); o[2] = f2bf(v.z); o[3] = f2bf(v.w);
        ((short4v*)dst)[i] = o;
    }
}

// transpose one [R][C] fp32 matrix per blockIdx.z into [C][R] bf16
__global__ void wtrans_kernel(const float* __restrict__ src, short* __restrict__ dst, int R, int C)
{
    __shared__ float t[32][33];
    int c0 = blockIdx.x * 32, r0 = blockIdx.y * 32;
    const float* s = src + (size_t)blockIdx.z * R * C;
    short* d = dst + (size_t)blockIdx.z * R * C;
    int cc = threadIdx.x & 31, rr = threadIdx.x >> 5;
#pragma unroll
    for (int pp = 0; pp < 4; ++pp)
        t[rr + pp * 8][cc] = s[(size_t)(r0 + rr + pp * 8) * C + c0 + cc];
    __syncthreads();
#pragma unroll
    for (int pp = 0; pp < 4; ++pp) {
        int c = rr + pp * 8;
        d[(size_t)(c0 + c) * R + r0 + cc] = f2bf(t[cc][c]);
    }
}

// ---------------- expert GEMMs (m97 structure) ----------------
// 128x128 tile, BK=64, 256 threads = 4 waves (2m x 2n), 64x64 per wave,
// linear LDS [128][64] bf16, global_load_lds width-16 staging, 2 barriers/K.

__global__ __launch_bounds__(256) void gemm1_kernel(
    const short* __restrict__ xbf, const short* __restrict__ w1t,
    const float* __restrict__ b1, const int* __restrict__ offs,
    const int* __restrict__ tile_e, const int* __restrict__ tile_m0,
    const int* __restrict__ list_tok, short* __restrict__ hbuf,
    int h0, int hlen)
{
    if ((int)blockIdx.x >= offs[17]) return;
    int e = tile_e[blockIdx.x], m0 = tile_m0[blockIdx.x];
    int rows = offs[e + 1] - m0; if (rows > GBM) rows = GBM;
    int n0 = blockIdx.y * GBN;            // chunk-relative h
    int tid = threadIdx.x, lane = tid & 63, w = tid >> 6;

    __shared__ __align__(16) short As[GBM * 64];
    __shared__ __align__(16) short Bs[GBN * 64];
    __shared__ int ts[GBM];
    if (tid < GBM) ts[tid] = list_tok[m0 + (tid < rows ? tid : rows - 1)];
    __syncthreads();

    // staging: wave w owns LDS rows [w*32, w*32+32); instr i stages 8 rows.
    int srow = w * 32 + (lane >> 3);
    int seg = (lane & 7) * 8;             // k-element offset of this lane's 16B
    const short* ga[4]; const short* gb[4];
#pragma unroll
    for (int i = 0; i < 4; ++i)
        ga[i] = xbf + (size_t)ts[srow + i * 8] * DDIM + seg;
    const short* brow = w1t + ((size_t)e * HDIM + (size_t)(h0 + n0) + srow) * DDIM + seg;
#pragma unroll
    for (int i = 0; i < 4; ++i)
        gb[i] = brow + (size_t)(i * 8) * DDIM;
    short* lA = As + w * 2048;
    short* lB = Bs + w * 2048;

    int wm = w >> 1, wn = w & 1;
    int a_r = wm * 64 + (lane & 15);
    int b_r = wn * 64 + (lane & 15);
    int kf = (lane >> 4) * 8;

    f32x4 vzero = {0.0f, 0.0f, 0.0f, 0.0f};
    f32x4 acc[4][4];
#pragma unroll
    for (int i = 0; i < 4; ++i)
#pragma unroll
        for (int j = 0; j < 4; ++j) acc[i][j] = vzero;

#pragma unroll 1
    for (int kb = 0; kb < DDIM / 64; ++kb) {
#pragma unroll
        for (int i = 0; i < 4; ++i) gload16(ga[i] + kb * 64, lA + i * 512);
#pragma unroll
        for (int i = 0; i < 4; ++i) gload16(gb[i] + kb * 64, lB + i * 512);
        __syncthreads();
#pragma unroll
        for (int ks = 0; ks < 2; ++ks) {
            short8 af[4], bfv[4];
            int ko = ks * 32 + kf;
#pragma unroll
            for (int mi = 0; mi < 4; ++mi)
                af[mi] = *(const short8*)(As + (a_r + mi * 16) * 64 + ko);
#pragma unroll
            for (int ni = 0; ni < 4; ++ni)
                bfv[ni] = *(const short8*)(Bs + (b_r + ni * 16) * 64 + ko);
#pragma unroll
            for (int mi = 0; mi < 4; ++mi)
#pragma unroll
                for (int ni = 0; ni < 4; ++ni)
                    acc[mi][ni] = __builtin_amdgcn_mfma_f32_16x16x32_bf16(
                        af[mi], bfv[ni], acc[mi][ni], 0, 0, 0);
        }
        __syncthreads();
    }

    int crow = wm * 64 + ((lane >> 4) << 2);
    int ccol = wn * 64 + (lane & 15);
#pragma unroll
    for (int mi = 0; mi < 4; ++mi) {
#pragma unroll
        for (int ni = 0; ni < 4; ++ni) {
            int col = ccol + ni * 16;
            float bias = b1[e * HDIM + h0 + n0 + col];
#pragma unroll
            for (int j = 0; j < 4; ++j) {
                int row = crow + mi * 16 + j;
                if (row < rows) {
                    float v = acc[mi][ni][j] + bias;
                    hbuf[(size_t)(m0 + row) * hlen + (n0 + col)] = f2bf(geluf(v));
                }
            }
        }
    }
}

__global__ __launch_bounds__(256) void gemm2_kernel(
    const short* __restrict__ hbuf, const short* __restrict__ w2t,
    const float* __restrict__ b2, const int* __restrict__ offs,
    const int* __restrict__ tile_e, const int* __restrict__ tile_m0,
    const int* __restrict__ list_tok, const float* __restrict__ list_w,
    float* __restrict__ ybuf, float* __restrict__ out,
    int h0, int hlen, int mode)
{
    if ((int)blockIdx.x >= offs[17]) return;
    int e = tile_e[blockIdx.x], m0 = tile_m0[blockIdx.x];
    int rows = offs[e + 1] - m0; if (rows > GBM) rows = GBM;
    int n0 = blockIdx.y * GBN;            // output d coordinate
    int tid = threadIdx.x, lane = tid & 63, w = tid >> 6;

    __shared__ __align__(16) short As[GBM * 64];
    __shared__ __align__(16) short Bs[GBN * 64];
    __shared__ int ts[GBM];
    __shared__ float lw[GBM];
    if (tid < GBM) {
        int idx = m0 + (tid < rows ? tid : rows - 1);
        ts[tid] = list_tok[idx];
        lw[tid] = list_w[idx];
    }
    __syncthreads();

    int srow = w * 32 + (lane >> 3);
    int seg = (lane & 7) * 8;
    const short* ga[4]; const short* gb[4];
#pragma unroll
    for (int i = 0; i < 4; ++i) {
        int slot = m0 + srow + i * 8; if (slot >= NSLOT) slot = NSLOT - 1;
        ga[i] = hbuf + (size_t)slot * hlen + seg;
    }
    const short* brow = w2t + ((size_t)e * DDIM + n0 + srow) * HDIM + h0 + seg;
#pragma unroll
    for (int i = 0; i < 4; ++i)
        gb[i] = brow + (size_t)(i * 8) * HDIM;
    short* lA = As + w * 2048;
    short* lB = Bs + w * 2048;

    int wm = w >> 1, wn = w & 1;
    int a_r = wm * 64 + (lane & 15);
    int b_r = wn * 64 + (lane & 15);
    int kf = (lane >> 4) * 8;

    f32x4 vzero = {0.0f, 0.0f, 0.0f, 0.0f};
    f32x4 acc[4][4];
#pragma unroll
    for (int i = 0; i < 4; ++i)
#pragma unroll
        for (int j = 0; j < 4; ++j) acc[i][j] = vzero;

    int nkb = hlen >> 6;
#pragma unroll 1
    for (int kb = 0; kb < nkb; ++kb) {
#pragma unroll
        for (int i = 0; i < 4; ++i) gload16(ga[i] + kb * 64, lA + i * 512);
#pragma unroll
        for (int i = 0; i < 4; ++i) gload16(gb[i] + kb * 64, lB + i * 512);
        __syncthreads();
#pragma unroll
        for (int ks = 0; ks < 2; ++ks) {
            short8 af[4], bfv[4];
            int ko = ks * 32 + kf;
#pragma unroll
            for (int mi = 0; mi < 4; ++mi)
                af[mi] = *(const short8*)(As + (a_r + mi * 16) * 64 + ko);
#pragma unroll
            for (int ni = 0; ni < 4; ++ni)
                bfv[ni] = *(const short8*)(Bs + (b_r + ni * 16) * 64 + ko);
#pragma unroll
            for (int mi = 0; mi < 4; ++mi)
#pragma unroll
                for (int ni = 0; ni < 4; ++ni)
                    acc[mi][ni] = __builtin_amdgcn_mfma_f32_16x16x32_bf16(
                        af[mi], bfv[ni], acc[mi][ni], 0, 0, 0);
        }
        __syncthreads();
    }

    int crow = wm * 64 + ((lane >> 4) << 2);
    int ccol = wn * 64 + (lane & 15);
#pragma unroll
    for (int mi = 0; mi < 4; ++mi) {
#pragma unroll
        for (int ni = 0; ni < 4; ++ni) {
            int col = ccol + ni * 16;
            float bias = (h0 == 0) ? b2[e * DDIM + n0 + col] : 0.0f;
#pragma unroll
            for (int j = 0; j < 4; ++j) {
                int row = crow + mi * 16 + j;
                if (row < rows) {
                    float v = acc[mi][ni][j] + bias;
                    if (mode == 0) {
                        float* yp = ybuf + (size_t)(m0 + row) * DDIM + n0 + col;
                        *yp = (h0 == 0) ? v : (*yp + v);
                    } else {
                        atomicAdd(&out[(size_t)ts[row] * DDIM + n0 + col], lw[row] * v);
                    }
                }
            }
        }
    }
}

// out[t] = w0*ybuf[pos0] + w1*ybuf[pos1]
__global__ __launch_bounds__(256) void combine_kernel(
    const float* __restrict__ ybuf, const int* __restrict__ pos_tk,
    const float* __restrict__ tok_w, float* __restrict__ out)
{
    int i = blockIdx.x * 256 + threadIdx.x;   // over T_TOK * 128 float4 units
    int t = i >> 7, c = i & 127;
    float w0 = tok_w[2 * t], w1 = tok_w[2 * t + 1];
    int p0 = pos_tk[2 * t], p1 = pos_tk[2 * t + 1];
    float4 a = ((const float4*)ybuf)[(size_t)p0 * 128 + c];
    float4 b = ((const float4*)ybuf)[(size_t)p1 * 128 + c];
    float4 o;
    o.x = w0 * a.x + w1 * b.x;
    o.y = w0 * a.y + w1 * b.y;
    o.z = w0 * a.z + w1 * b.z;
    o.w = w0 * a.w + w1 * b.w;
    ((float4*)out)[(size_t)t * 128 + c] = o;
}

// ---------------- launch ----------------

extern "C" void kernel_launch(void* const* d_in, const int* in_sizes, int n_in,
                              void* d_out, int out_size, void* d_ws, size_t ws_size,
                              hipStream_t stream)
{
    const float* x  = (const float*)d_in[0];
    const float* wg = (const float*)d_in[1];
    const float* bg = (const float*)d_in[2];
    const float* w1 = (const float*)d_in[3];
    const float* b1 = (const float*)d_in[4];
    const float* w2 = (const float*)d_in[5];
    const float* b2 = (const float*)d_in[6];
    float* out = (float*)d_out;

    char* p = (char*)d_ws;
    int* counts   = (int*)(p);                  // 64 B
    int* cursors  = (int*)(p + 64);             // 64 B
    int* offs     = (int*)(p + 128);            // 32 ints
    int* tile_e   = (int*)(p + 256);            // 512 ints
    int* tile_m0  = (int*)(p + 2304);           // 512 ints
    int* tok_e    = (int*)(p + 8192);           // 128 KiB
    float* tok_w  = (float*)(p + 8192 + 131072);
    int* list_tok = (int*)(p + 8192 + 262144);
    float* list_w = (float*)(p + 8192 + 393216);
    int* pos_tk   = (int*)(p + 8192 + 524288);
    short* xbf    = (short*)(p + 8192 + 655360);              // 16 MiB
    short* w1t    = xbf + (size_t)T_TOK * DDIM;               // 32 MiB
    short* w2t    = w1t + (size_t)NEXP * DDIM * HDIM;         // 32 MiB
    char* after   = (char*)(w2t + (size_t)NEXP * DDIM * HDIM);
    size_t fixed  = (size_t)(after - p);

    // prefer slot-buffer (no atomics); fall back to atomic accumulate
    int hlen = 0, mode = 0;
    for (int hl = HDIM; hl >= 128; hl >>= 1)
        if (fixed + (size_t)NSLOT * DDIM * 4 + (size_t)NSLOT * hl * 2 <= ws_size) { hlen = hl; mode = 0; break; }
    if (!hlen)
        for (int hl = HDIM; hl >= 128; hl >>= 1)
            if (fixed + (size_t)NSLOT * hl * 2 <= ws_size) { hlen = hl; mode = 1; break; }

    float* ybuf = (float*)after;
    short* hbuf = (mode == 0) ? (short*)(after + (size_t)NSLOT * DDIM * 4) : (short*)after;

    if (!hlen) { hipMemsetAsync(d_out, 0, (size_t)out_size * sizeof(float), stream); return; }
    if (mode == 1) hipMemsetAsync(d_out, 0, (size_t)out_size * sizeof(float), stream);
    hipMemsetAsync(counts, 0, 64, stream);

    gate_kernel<<<T_TOK / 16, 256, 0, stream>>>(x, wg, bg, tok_e, tok_w, counts);
    scan_kernel<<<1, 64, 0, stream>>>(counts, offs, cursors, tile_e, tile_m0);
    scatter_kernel<<<T_TOK / 256, 256, 0, stream>>>(tok_e, tok_w, cursors, list_tok, list_w, pos_tk);
    cvt_bf16_kernel<<<2048, 256, 0, stream>>>(x, xbf, T_TOK * DDIM / 4);
    wtrans_kernel<<<dim3(HDIM / 32, DDIM / 32, NEXP), 256, 0, stream>>>(w1, w1t, DDIM, HDIM);
    wtrans_kernel<<<dim3(DDIM / 32, HDIM / 32, NEXP), 256, 0, stream>>>(w2, w2t, HDIM, DDIM);

    for (int h0 = 0; h0 < HDIM; h0 += hlen) {
        gemm1_kernel<<<dim3(MAXTILE, hlen / GBN), 256, 0, stream>>>(
            xbf, w1t, b1, offs, tile_e, tile_m0, list_tok, hbuf, h0, hlen);
        gemm2_kernel<<<dim3(MAXTILE, DDIM / GBN), 256, 0, stream>>>(
            hbuf, w2t, b2, offs, tile_e, tile_m0, list_tok, list_w, ybuf, out, h0, hlen, mode);
    }
    if (mode == 0)
        combine_kernel<<<T_TOK * 128 / 256, 256, 0, stream>>>(ybuf, pos_tk, tok_w, out);
}